// Round 2
// baseline (114.283 us; speedup 1.0000x reference)
//
#include <hip/hip_runtime.h>

// SSIM loss, fused, barrier-free.
// inputs: img1, img2 float32 (16,3,512,512); output: float32 [16]
//
// Decomposition: grid = (batch, chan, 32 row-strips); block = 320 (5 waves).
// Each wave independently owns a 128-column slab (2 cols/lane as float2):
//   - vertical sliding 11-row column sums of {x1,x2,x1^2,x2^2,x1*x2} in regs
//   - horizontal 11-window via full-wave __shfl_down (ds_bpermute: no banks,
//     no LDS arrays, no __syncthreads anywhere in the hot loop)
//   - SSIM per pixel, per-lane accumulate -> wave shuffle-reduce ->
//     atomicAdd(double) -> tiny finalize kernel.
// Wave column bases {0,118,236,354,384}: each wave emits 118 output cols
// (lanes 0..58 x 2), last wave masked to cols 472..501. All loads in-bounds.

namespace {
constexpr int BATCH = 16;
constexpr int CHAN  = 3;
constexpr int HDIM  = 512;
constexpr int WDIM  = 512;
constexpr int WIN   = 11;
constexpr int HO    = HDIM - WIN + 1;   // 502
constexpr int WO    = WDIM - WIN + 1;   // 502
constexpr int NSTRIPS = 32;
constexpr int RPS   = 16;               // ceil(502/32)
constexpr int NWAVES = 5;
constexpr int NTHR  = NWAVES * 64;      // 320
constexpr float C1F = 6.5025f;          // (0.01*255)^2
constexpr float C2F = 58.5225f;         // (0.03*255)^2
constexpr float INVW2 = 1.0f / 121.0f;
}

__device__ __forceinline__ float ssim_px(float v1, float v2, float v11,
                                         float v22, float v12) {
  float mu1 = v1 * INVW2, mu2 = v2 * INVW2;
  float mu1sq = mu1 * mu1, mu2sq = mu2 * mu2, mu12 = mu1 * mu2;
  float sig1 = fmaf(v11, INVW2, -mu1sq);
  float sig2 = fmaf(v22, INVW2, -mu2sq);
  float sg12 = fmaf(v12, INVW2, -mu12);
  float n = (2.0f * mu12 + C1F) * (2.0f * sg12 + C2F);
  float d = (mu1sq + mu2sq + C1F) * (sig1 + sig2 + C2F);
  return n / d;
}

__global__ __launch_bounds__(NTHR) void ssim_main(
    const float* __restrict__ g1, const float* __restrict__ g2,
    double* __restrict__ ws) {
  const int t  = threadIdx.x;
  const int wv = t >> 6;
  const int L  = t & 63;

  const int bid   = blockIdx.x;
  const int strip = bid % NSTRIPS;
  const int bc    = bid / NSTRIPS;
  const int b     = bc / CHAN;
  const int c     = bc % CHAN;
  const int r0    = strip * RPS;
  const int r1    = min(r0 + RPS, HO);

  const int c0   = min(118 * wv, 384);   // wave's first input column
  const int o_lo = min(118 * wv, 472);   // wave's first OWNED output column
  const bool valid = (L <= 58) && (c0 + 2 * L >= o_lo);

  const float* __restrict__ p1 =
      g1 + (size_t)(b * CHAN + c) * HDIM * WDIM + c0 + 2 * L;
  const float* __restrict__ p2 =
      g2 + (size_t)(b * CHAN + c) * HDIM * WDIM + c0 + 2 * L;

  // vertical 11-row sliding sums for this lane's 2 columns
  float a1x = 0, a1y = 0, a2x = 0, a2y = 0;
  float a11x = 0, a11y = 0, a22x = 0, a22y = 0, a12x = 0, a12y = 0;

  auto addrow = [&](int row) {
    float2 u = *(const float2*)(p1 + (size_t)row * WDIM);
    float2 v = *(const float2*)(p2 + (size_t)row * WDIM);
    a1x += u.x;  a1y += u.y;
    a2x += v.x;  a2y += v.y;
    a11x = fmaf(u.x, u.x, a11x);  a11y = fmaf(u.y, u.y, a11y);
    a22x = fmaf(v.x, v.x, a22x);  a22y = fmaf(v.y, v.y, a22y);
    a12x = fmaf(u.x, v.x, a12x);  a12y = fmaf(u.y, v.y, a12y);
  };
  auto subrow = [&](int row) {
    float2 u = *(const float2*)(p1 + (size_t)row * WDIM);
    float2 v = *(const float2*)(p2 + (size_t)row * WDIM);
    a1x -= u.x;  a1y -= u.y;
    a2x -= v.x;  a2y -= v.y;
    a11x = fmaf(u.x, -u.x, a11x);  a11y = fmaf(u.y, -u.y, a11y);
    a22x = fmaf(v.x, -v.x, a22x);  a22y = fmaf(v.y, -v.y, a22y);
    a12x = fmaf(u.x, -v.x, a12x);  a12y = fmaf(u.y, -v.y, a12y);
  };

  // horizontal 11-window from per-lane pair sums via full-wave shuffles:
  // S0(col 2L+c0)  = s_L + s_{L+1} + s_{L+2} + s_{L+3} + s_{L+4} + x_{L+5}
  // S1(col 2L+1+..) = S0 - x_L + y_{L+5}
  auto hwin = [&](float x, float y, float& S0, float& S1) {
    float s  = x + y;
    float t1 = s + __shfl_down(s, 1, 64);
    float t2 = t1 + __shfl_down(t1, 2, 64);
    float S  = t2 + __shfl_down(s, 4, 64) + __shfl_down(x, 5, 64);
    S0 = S;
    S1 = S - x + __shfl_down(y, 5, 64);
  };

  // warm-up: rows r0 .. r0+9 (window will be completed in the loop)
#pragma unroll
  for (int dy = 0; dy < WIN - 1; ++dy) addrow(r0 + dy);

  float acc = 0.0f;
  for (int r = r0; r < r1; ++r) {
    addrow(r + WIN - 1);  // window now holds rows [r, r+10]

    float s1a, s1b, s2a, s2b, s11a, s11b, s22a, s22b, s12a, s12b;
    hwin(a1x,  a1y,  s1a,  s1b);
    hwin(a2x,  a2y,  s2a,  s2b);
    hwin(a11x, a11y, s11a, s11b);
    hwin(a22x, a22y, s22a, s22b);
    hwin(a12x, a12y, s12a, s12b);

    if (valid) {
      acc += ssim_px(s1a, s2a, s11a, s22a, s12a);
      acc += ssim_px(s1b, s2b, s11b, s22b, s12b);
    }

    subrow(r);            // prep window for next iteration (cache re-read)
  }

  // wave reduction, then one double atomic per wave
#pragma unroll
  for (int off = 32; off > 0; off >>= 1) acc += __shfl_down(acc, off, 64);
  if (L == 0) atomicAdd(&ws[b], (double)acc);
}

__global__ void ssim_finalize(const double* __restrict__ ws,
                              float* __restrict__ out) {
  int i = threadIdx.x;
  if (i < BATCH) {
    double mean = ws[i] / ((double)CHAN * HO * WO);
    out[i] = (float)(1.0 - mean);
  }
}

extern "C" void kernel_launch(void* const* d_in, const int* in_sizes, int n_in,
                              void* d_out, int out_size, void* d_ws,
                              size_t ws_size, hipStream_t stream) {
  const float* img1 = (const float*)d_in[0];
  const float* img2 = (const float*)d_in[1];
  float* out = (float*)d_out;
  double* ws = (double*)d_ws;

  hipMemsetAsync(d_ws, 0, BATCH * sizeof(double), stream);
  ssim_main<<<dim3(BATCH * CHAN * NSTRIPS), NTHR, 0, stream>>>(img1, img2, ws);
  ssim_finalize<<<1, 64, 0, stream>>>(ws, out);
}

// Round 3
// 53.280 us; speedup vs baseline: 2.1450x; 2.1450x over previous
//
#include <hip/hip_runtime.h>

// SSIM loss, fused single pass. inputs: img1,img2 f32 (16,3,512,512); out f32[16].
//
// Structure (round-1 LDS design + latency fixes):
//  grid = (16 batch × 3 chan × 32 row-strips) = 1536 blocks, 256 thr (4 waves).
//  Per block: vertical sliding 11-row column sums of {x1,x2,x1²,x2²,x1·x2}
//  in registers (2 cols/thread = 512 cols), published per output row into
//  DOUBLE-BUFFERED swizzled LDS arrays; ONE raw barrier per row
//  (s_waitcnt lgkmcnt(0); s_barrier — leaves global prefetch in flight);
//  horizontal 11-window from LDS (6×ds_read_b64, pad-swizzled); SSIM per px
//  with v_rcp; block tree-reduce -> atomicAdd(double) -> finalize kernel.
//
// Race argument for the single barrier + double buffer: reads of V[p] at
// iter r are forced complete by the lgkmcnt(0) inside barrier(r+1); the next
// write to V[p] is at iter r+2, after barrier(r+1). Writes of V[p] at iter r
// are visible to readers because lgkmcnt(0) precedes s_barrier in one asm.

namespace {
constexpr int BATCH = 16;
constexpr int CHAN  = 3;
constexpr int HDIM  = 512;
constexpr int WDIM  = 512;
constexpr int WIN   = 11;
constexpr int HO    = HDIM - WIN + 1;   // 502
constexpr int WO    = WDIM - WIN + 1;   // 502
constexpr int NSTRIPS = 32;
constexpr int RPS   = 16;               // ceil(502/32); last strip does 6
constexpr int NTHR  = 256;
constexpr float C1F = 6.5025f;          // (0.01*255)^2
constexpr float C2F = 58.5225f;         // (0.03*255)^2
constexpr float INVW2 = 1.0f / 121.0f;
constexpr int VLEN = 544;               // swz(510)+2, padded
}

// +2 words every 32: breaks power-of-2 stride collisions, keeps 8B alignment.
__device__ __forceinline__ int swz(int x) { return x + 2 * (x >> 5); }

__device__ __forceinline__ float ssim_px(float v1, float v2, float v11,
                                         float v22, float v12) {
  float mu1 = v1 * INVW2, mu2 = v2 * INVW2;
  float mu1sq = mu1 * mu1, mu2sq = mu2 * mu2, mu12 = mu1 * mu2;
  float sig1 = fmaf(v11, INVW2, -mu1sq);
  float sig2 = fmaf(v22, INVW2, -mu2sq);
  float sg12 = fmaf(v12, INVW2, -mu12);
  float n = (2.0f * mu12 + C1F) * (2.0f * sg12 + C2F);
  float d = (mu1sq + mu2sq + C1F) * (sig1 + sig2 + C2F);
  return n * __builtin_amdgcn_rcpf(d);   // 1-ulp rcp, threshold is 6e-5
}

__global__ __launch_bounds__(NTHR) void ssim_main(
    const float* __restrict__ g1, const float* __restrict__ g2,
    double* __restrict__ ws) {
  __shared__ float V[2][5][VLEN];
  __shared__ float red[NTHR];

  const int bid   = blockIdx.x;
  const int strip = bid % NSTRIPS;
  const int bc    = bid / NSTRIPS;
  const int b     = bc / CHAN;
  const int c     = bc % CHAN;
  const int r0    = strip * RPS;
  const int r1    = min(r0 + RPS, HO);

  const int t  = threadIdx.x;
  const int x0 = 2 * t;                 // this thread's two columns
  const int w  = swz(x0);

  const float* __restrict__ p1 = g1 + (size_t)(b * CHAN + c) * HDIM * WDIM;
  const float* __restrict__ p2 = g2 + (size_t)(b * CHAN + c) * HDIM * WDIM;

  // vertical 11-row sliding sums for columns x0, x0+1
  float a1x = 0, a1y = 0, a2x = 0, a2y = 0;
  float a11x = 0, a11y = 0, a22x = 0, a22y = 0, a12x = 0, a12y = 0;

#pragma unroll
  for (int dy = 0; dy < WIN; ++dy) {
    float2 u = *(const float2*)(p1 + (size_t)(r0 + dy) * WDIM + x0);
    float2 v = *(const float2*)(p2 + (size_t)(r0 + dy) * WDIM + x0);
    a1x += u.x;  a1y += u.y;
    a2x += v.x;  a2y += v.y;
    a11x = fmaf(u.x, u.x, a11x);  a11y = fmaf(u.y, u.y, a11y);
    a22x = fmaf(v.x, v.x, a22x);  a22y = fmaf(v.y, v.y, a22y);
    a12x = fmaf(u.x, v.x, a12x);  a12y = fmaf(u.y, v.y, a12y);
  }

  float acc = 0.0f;

  for (int r = r0; r < r1; ++r) {
    const int pb = (r - r0) & 1;
    float (* __restrict__ Vb)[VLEN] = V[pb];

    // 1. prefetch next slide rows (used at step 5; stays in flight across
    //    the barrier — the raw barrier below waits lgkmcnt only)
    const bool hasnext = (r + 1 < r1);
    float2 un, vn, uo, vo;
    if (hasnext) {
      un = *(const float2*)(p1 + (size_t)(r + WIN) * WDIM + x0);
      vn = *(const float2*)(p2 + (size_t)(r + WIN) * WDIM + x0);
      uo = *(const float2*)(p1 + (size_t)r * WDIM + x0);
      vo = *(const float2*)(p2 + (size_t)r * WDIM + x0);
    }

    // 2. publish this row's column sums
    *(float2*)&Vb[0][w] = make_float2(a1x, a1y);
    *(float2*)&Vb[1][w] = make_float2(a2x, a2y);
    *(float2*)&Vb[2][w] = make_float2(a11x, a11y);
    *(float2*)&Vb[3][w] = make_float2(a22x, a22y);
    *(float2*)&Vb[4][w] = make_float2(a12x, a12y);

    // 3. LDS-only barrier (global prefetch NOT drained)
    asm volatile("s_waitcnt lgkmcnt(0)\n\ts_barrier" ::: "memory");

    // 4. horizontal 11-window + SSIM for output cols x0, x0+1
    if (x0 < WO) {
      float s1a, s1b, s2a, s2b, s11a, s11b, s22a, s22b, s12a, s12b;
      auto hsum = [&](const float* vq, float& S0, float& S1) {
        float2 q0 = *(const float2*)(vq + swz(x0 + 0));
        float2 q1 = *(const float2*)(vq + swz(x0 + 2));
        float2 q2 = *(const float2*)(vq + swz(x0 + 4));
        float2 q3 = *(const float2*)(vq + swz(x0 + 6));
        float2 q4 = *(const float2*)(vq + swz(x0 + 8));
        float2 q5 = *(const float2*)(vq + swz(x0 + 10));
        S0 = ((q0.x + q0.y) + (q1.x + q1.y)) +
             ((q2.x + q2.y) + (q3.x + q3.y)) + ((q4.x + q4.y) + q5.x);
        S1 = (S0 - q0.x) + q5.y;
      };
      hsum(Vb[0], s1a, s1b);
      hsum(Vb[1], s2a, s2b);
      hsum(Vb[2], s11a, s11b);
      hsum(Vb[3], s22a, s22b);
      hsum(Vb[4], s12a, s12b);
      acc += ssim_px(s1a, s2a, s11a, s22a, s12a);
      acc += ssim_px(s1b, s2b, s11b, s22b, s12b);
    }

    // 5. apply slide using prefetched rows (vmcnt wait lands here)
    if (hasnext) {
      a1x += un.x - uo.x;  a1y += un.y - uo.y;
      a2x += vn.x - vo.x;  a2y += vn.y - vo.y;
      a11x = fmaf(un.x, un.x, fmaf(uo.x, -uo.x, a11x));
      a11y = fmaf(un.y, un.y, fmaf(uo.y, -uo.y, a11y));
      a22x = fmaf(vn.x, vn.x, fmaf(vo.x, -vo.x, a22x));
      a22y = fmaf(vn.y, vn.y, fmaf(vo.y, -vo.y, a22y));
      a12x = fmaf(un.x, vn.x, fmaf(uo.x, -vo.x, a12x));
      a12y = fmaf(un.y, vn.y, fmaf(uo.y, -vo.y, a12y));
    }
  }

  // block reduction (cold path: normal barriers fine)
  __syncthreads();
  red[t] = acc;
  __syncthreads();
#pragma unroll
  for (int s = NTHR / 2; s > 0; s >>= 1) {
    if (t < s) red[t] += red[t + s];
    __syncthreads();
  }
  if (t == 0) atomicAdd(&ws[b], (double)red[0]);
}

__global__ void ssim_finalize(const double* __restrict__ ws,
                              float* __restrict__ out) {
  int i = threadIdx.x;
  if (i < BATCH) {
    double mean = ws[i] / ((double)CHAN * HO * WO);
    out[i] = (float)(1.0 - mean);
  }
}

extern "C" void kernel_launch(void* const* d_in, const int* in_sizes, int n_in,
                              void* d_out, int out_size, void* d_ws,
                              size_t ws_size, hipStream_t stream) {
  const float* img1 = (const float*)d_in[0];
  const float* img2 = (const float*)d_in[1];
  float* out = (float*)d_out;
  double* ws = (double*)d_ws;

  hipMemsetAsync(d_ws, 0, BATCH * sizeof(double), stream);
  ssim_main<<<dim3(BATCH * CHAN * NSTRIPS), NTHR, 0, stream>>>(img1, img2, ws);
  ssim_finalize<<<1, 64, 0, stream>>>(ws, out);
}